// Round 2
// baseline (755.536 us; speedup 1.0000x reference)
//
#include <hip/hip_runtime.h>
#include <cmath>

// Problem constants
#define NROWS 16384
#define DDIM  512

typedef __attribute__((ext_vector_type(8))) short          bf16x8;
typedef __attribute__((ext_vector_type(4))) float          f32x4;
typedef __attribute__((ext_vector_type(8))) unsigned short u16x8;
typedef __attribute__((ext_vector_type(4))) unsigned short u16x4;

__device__ __forceinline__ unsigned short f2bf(float f) {
  unsigned u = __float_as_uint(f);
  u += 0x7fffu + ((u >> 16) & 1u);  // RNE; inputs finite
  return (unsigned short)(u >> 16);
}

__device__ __forceinline__ float gelu_tanh(float x) {
  float x3 = x * x * x;
  float t = tanhf(0.79788456080286535588f * (x + 0.044715f * x3));
  return 0.5f * x * (1.0f + t);
}

__device__ __forceinline__ void ld8(const float* p, float* v) {
  float4 a = *(const float4*)p;
  float4 b = *(const float4*)(p + 256);
  v[0] = a.x; v[1] = a.y; v[2] = a.z; v[3] = a.w;
  v[4] = b.x; v[5] = b.y; v[6] = b.z; v[7] = b.w;
}

__device__ __forceinline__ void st8(float* p, const float* v) {
  *(float4*)p = make_float4(v[0], v[1], v[2], v[3]);
  *(float4*)(p + 256) = make_float4(v[4], v[5], v[6], v[7]);
}

__device__ __forceinline__ float wave_sum(float v) {
#pragma unroll
  for (int m = 1; m < 64; m <<= 1) v += __shfl_xor(v, m, 64);
  return v;
}

// ---------------------------------------------------------------------------
// Kernel 1: per-row prep. Gate numerics FROZEN (same fp64 chain, bit-identical:
// fp32 weights are converted to fp64 at use via exact v_cvt_f64_f32 instead of
// being pre-converted into 96 pinned VGPRs).
// Round-5 changes (evidence: VGPR=132 -> 3 waves/SIMD; atomic WRITE traffic
// 16.8MB serialized cross-XCD):
//   - weights stay fp32 scalars (SGPRs), cvt at use -> frees ~96 VGPRs
//   - __launch_bounds__(256,4) -> <=128 VGPR, 4 waves/SIMD
//   - stats spread over 32 atomic copies (blockIdx&31) -> 64 adds/addr/copy
// ---------------------------------------------------------------------------
__global__ __launch_bounds__(256, 4) void prep_kernel(
    const float* __restrict__ img, const float* __restrict__ txt,
    const float* __restrict__ wg_w1, const float* __restrict__ wg_b1,
    const float* __restrict__ wg_w2, const float* __restrict__ wg_b2,
    const float* __restrict__ conv_w, const float* __restrict__ conv_b,
    unsigned short* __restrict__ xbf, unsigned short* __restrict__ imgbf,
    float* __restrict__ accPart) {
  __shared__ float csX[512], cqX[512], csI[512], cqI[512];
  const int tid = threadIdx.x;
  for (int i = tid; i < 512; i += 256) {
    csX[i] = 0.f; cqX[i] = 0.f; csI[i] = 0.f; cqI[i] = 0.f;
  }
  __syncthreads();

  const int lane = tid & 63;
  const int gwave = blockIdx.x * 4 + (tid >> 6);  // 0..8191

  const float cb = conv_b[0];
  const float b2f = wg_b2[0];
  // keep as fp32 (uniform -> SGPRs); convert to fp64 at use (exact)
  float w1f[16], b1f[16], w2f[16];
#pragma unroll
  for (int i = 0; i < 16; i++) {
    w1f[i] = wg_w1[i]; b1f[i] = wg_b1[i]; w2f[i] = wg_w2[i];
  }
  float cw[5];
#pragma unroll
  for (int k = 0; k < 5; k++) cw[k] = conv_w[k];

  float sX[8] = {0, 0, 0, 0, 0, 0, 0, 0}, qX[8] = {0, 0, 0, 0, 0, 0, 0, 0};
  float sI[8] = {0, 0, 0, 0, 0, 0, 0, 0}, qI[8] = {0, 0, 0, 0, 0, 0, 0, 0};

  for (int it = 0; it < 2; it++) {
    const int r = gwave * 2 + it;
    const float* ip = img + (size_t)r * DDIM + lane * 4;
    float iv[8];
    ld8(ip, iv);
    double ss = 0.0;
#pragma unroll
    for (int j = 0; j < 8; j++) ss += (double)iv[j] * (double)iv[j];
#pragma unroll
    for (int m = 1; m < 64; m <<= 1) ss += __shfl_xor(ss, m, 64);
    const double dimg = fmax(sqrt(ss), 1e-12);

    // img -> bf16 (same f2bf rounding the old cvt_kernel used)
    {
      u16x4 lo, hi;
#pragma unroll
      for (int j = 0; j < 4; j++) { lo[j] = f2bf(iv[j]); hi[j] = f2bf(iv[4 + j]); }
      *(u16x4*)(imgbf + (size_t)r * DDIM + lane * 4) = lo;
      *(u16x4*)(imgbf + (size_t)r * DDIM + 256 + lane * 4) = hi;
    }

    float tv[5][8];
    double simv[5];
#pragma unroll
    for (int k = 0; k < 5; k++) {
      const float* tp = txt + ((size_t)r * 5 + k) * DDIM + lane * 4;
      ld8(tp, tv[k]);
      double s2 = 0.0, dp = 0.0;
#pragma unroll
      for (int j = 0; j < 8; j++) {
        s2 += (double)tv[k][j] * (double)tv[k][j];
        dp += (double)iv[j] * (double)tv[k][j];
      }
#pragma unroll
      for (int m = 1; m < 64; m <<= 1) {
        s2 += __shfl_xor(s2, m, 64);
        dp += __shfl_xor(dp, m, 64);
      }
      const double dt = fmax(sqrt(s2), 1e-12);
      simv[k] = dp / (dimg * dt);
    }

    // WeightGate logit in fp64 (true ordering), sigmoid emulating fp32 chain
    float wv[5];
#pragma unroll
    for (int k = 0; k < 5; k++) {
      double o = (double)b2f;
#pragma unroll
      for (int i = 0; i < 16; i++) {
        double h = simv[k] * (double)w1f[i] + (double)b1f[i];
        h = fmax(h, 0.0);
        o += h * (double)w2f[i];
      }
      float o32 = (float)o;
      float e32 = (float)exp(-(double)o32);  // correctly-rounded f32 exp
      float a32 = 1.0f + e32;
      wv[k] = 1.0f / a32;
    }

    // stable descending rank -> coefficient
    float c[5];
#pragma unroll
    for (int k = 0; k < 5; k++) {
      int rk = 0;
#pragma unroll
      for (int j = 0; j < 5; j++)
        rk += (int)((wv[j] > wv[k]) || ((wv[j] == wv[k]) && (j < k)));
      c[k] = cw[rk] * wv[k];
    }

    float xv[8];
#pragma unroll
    for (int j = 0; j < 8; j++) {
      float v = cb;
#pragma unroll
      for (int k = 0; k < 5; k++) v = fmaf(c[k], tv[k][j], v);
      xv[j] = v;
    }
    {
      u16x4 lo, hi;
#pragma unroll
      for (int j = 0; j < 4; j++) { lo[j] = f2bf(xv[j]); hi[j] = f2bf(xv[4 + j]); }
      *(u16x4*)(xbf + (size_t)r * DDIM + lane * 4) = lo;
      *(u16x4*)(xbf + (size_t)r * DDIM + 256 + lane * 4) = hi;
    }

#pragma unroll
    for (int j = 0; j < 8; j++) {
      sX[j] += xv[j]; qX[j] += xv[j] * xv[j];
      sI[j] += iv[j]; qI[j] += iv[j] * iv[j];
    }
  }

  const int c0 = lane * 4, c1 = 256 + lane * 4;
#pragma unroll
  for (int j = 0; j < 4; j++) {
    atomicAdd(&csX[c0 + j], sX[j]);     atomicAdd(&cqX[c0 + j], qX[j]);
    atomicAdd(&csX[c1 + j], sX[4 + j]); atomicAdd(&cqX[c1 + j], qX[4 + j]);
    atomicAdd(&csI[c0 + j], sI[j]);     atomicAdd(&cqI[c0 + j], qI[j]);
    atomicAdd(&csI[c1 + j], sI[4 + j]); atomicAdd(&cqI[c1 + j], qI[4 + j]);
  }
  __syncthreads();
  // 32-copy spread: [copy][{Xs,Xq,Is,Iq}][512]
  float* base = accPart + (size_t)(blockIdx.x & 31) * 2048;
  for (int i = tid; i < 512; i += 256) {
    atomicAdd(&base[i], csX[i]);
    atomicAdd(&base[512 + i], cqX[i]);
    atomicAdd(&base[1024 + i], csI[i]);
    atomicAdd(&base[1536 + i], cqI[i]);
  }
}

// ---------------------------------------------------------------------------
// finalize: (optionally multi-copy) BN stats -> affine
// scale = g*rstd, shift = b - mean*scale
// ---------------------------------------------------------------------------
__global__ void finalize_kernel(const float* __restrict__ s, const float* __restrict__ q,
                                const float* __restrict__ g, const float* __restrict__ b,
                                float* __restrict__ scale, float* __restrict__ shift,
                                float invM, int ncopies, int stride) {
  int j = threadIdx.x;
  if (j >= 512) return;
  float ss = 0.f, qq = 0.f;
  for (int c = 0; c < ncopies; c++) {
    ss += s[(size_t)c * stride + j];
    qq += q[(size_t)c * stride + j];
  }
  float m = ss * invM;
  float v = qq * invM - m * m;
  float r = 1.0f / sqrtf(v + 1e-5f);
  float sc = g[j] * r;
  scale[j] = sc;
  shift[j] = fmaf(-m, sc, b[j]);
}

// ---------------------------------------------------------------------------
// Weight prep: Wt[n][k] = bf16(scale[k] * W[k][n])  (transpose + fold BN scale)
//              addv[n] += sum_k shift[k] * W[k][n]  (exact fp32 shift term)
// grid (16,16), 32x32 tile per block.
// ---------------------------------------------------------------------------
__global__ __launch_bounds__(256) void wconv_kernel(
    const float* __restrict__ W, const float* __restrict__ scale,
    const float* __restrict__ shift, unsigned short* __restrict__ Wt,
    float* __restrict__ addv) {
  __shared__ float T[32][33];
  __shared__ float P[32];
  const int t = threadIdx.x;
  const int k0 = blockIdx.x * 32, n0 = blockIdx.y * 32;
  {
    int r = t >> 3, c = (t & 7) * 4;
    float4 v = *(const float4*)&W[(size_t)(k0 + r) * 512 + n0 + c];
    T[r][c] = v.x; T[r][c + 1] = v.y; T[r][c + 2] = v.z; T[r][c + 3] = v.w;
  }
  if (t < 32) P[t] = 0.f;
  __syncthreads();
  {
    int n = t >> 3, k = (t & 7) * 4;
    u16x4 o;
#pragma unroll
    for (int i = 0; i < 4; i++) o[i] = f2bf(T[k + i][n] * scale[k0 + k + i]);
    *(u16x4*)&Wt[(size_t)(n0 + n) * 512 + k0 + k] = o;
  }
  {
    int n = t & 31, rb = (t >> 5) * 4;
    float p = 0.f;
#pragma unroll
    for (int i = 0; i < 4; i++) p += shift[k0 + rb + i] * T[rb + i][n];
    atomicAdd(&P[n], p);
  }
  __syncthreads();
  if (t < 32) atomicAdd(&addv[n0 + t], P[t]);
}

// ---------------------------------------------------------------------------
// bf16 MFMA GEMM: C = act( A @ Wt^T + bias + addv ), A:[16384,512] bf16,
// Wt:[512,512] bf16 stored [n][k]. Tile 128x128, BK=32, 4 waves (2x2),
// 16x16x32 MFMA, 4x4 tiles/wave. LDS XOR-swizzle (kl ^= (row>>1)&3) makes
// ds_read_b128 frag loads conflict-free. Register-prefetched staging.
// Output: bf16 (Cb, feeds next GEMM) or fp32 (Cf, final). Optional col stats.
// ---------------------------------------------------------------------------
__global__ __launch_bounds__(256) void gemm_bf16(
    const unsigned short* __restrict__ A, const unsigned short* __restrict__ Wt,
    const float* __restrict__ bias, const float* __restrict__ addv,
    float* __restrict__ Cf, unsigned short* __restrict__ Cb, int do_gelu,
    float* __restrict__ accS, float* __restrict__ accQ) {
  __shared__ __align__(16) short As[128 * 32];
  __shared__ __align__(16) short Bs[128 * 32];
  __shared__ float colS[128], colQ[128];
  const int tid = threadIdx.x;
  const int ln = tid & 63;
  const int lq = ln >> 4, lr = ln & 15;
  const int wv = tid >> 6;
  const int wm = wv >> 1, wn = wv & 1;
  const int bm = blockIdx.x * 128, bn = blockIdx.y * 128;

  f32x4 acc[4][4];
#pragma unroll
  for (int i = 0; i < 4; i++)
#pragma unroll
    for (int j = 0; j < 4; j++) acc[i][j] = (f32x4){0.f, 0.f, 0.f, 0.f};

  // staging addresses: thread covers LDS 16B slots idx0, idx1 (512 slots/matrix)
  const int idx0 = tid, idx1 = 256 + tid;
  const int r0 = idx0 >> 2, k0g = (idx0 & 3) ^ ((r0 >> 1) & 3);
  const int r1 = idx1 >> 2, k1g = (idx1 & 3) ^ ((r1 >> 1) & 3);
  const unsigned short* ga0 = A + (size_t)(bm + r0) * 512 + k0g * 8;
  const unsigned short* ga1 = A + (size_t)(bm + r1) * 512 + k1g * 8;
  const unsigned short* gb0 = Wt + (size_t)(bn + r0) * 512 + k0g * 8;
  const unsigned short* gb1 = Wt + (size_t)(bn + r1) * 512 + k1g * 8;

  u16x8 va0 = *(const u16x8*)ga0, va1 = *(const u16x8*)ga1;
  u16x8 vb0 = *(const u16x8*)gb0, vb1 = *(const u16x8*)gb1;

  for (int kk = 0; kk < 512; kk += 32) {
    *(u16x8*)((char*)As + idx0 * 16) = va0;
    *(u16x8*)((char*)As + idx1 * 16) = va1;
    *(u16x8*)((char*)Bs + idx0 * 16) = vb0;
    *(u16x8*)((char*)Bs + idx1 * 16) = vb1;
    __syncthreads();
    if (kk + 32 < 512) {
      va0 = *(const u16x8*)(ga0 + kk + 32);
      va1 = *(const u16x8*)(ga1 + kk + 32);
      vb0 = *(const u16x8*)(gb0 + kk + 32);
      vb1 = *(const u16x8*)(gb1 + kk + 32);
    }
    bf16x8 af[4], bfr[4];
#pragma unroll
    for (int i = 0; i < 4; i++) {
      int r = wm * 64 + i * 16 + lr;
      af[i] = *(const bf16x8*)((const char*)As + r * 64 + ((lq ^ ((r >> 1) & 3)) << 4));
    }
#pragma unroll
    for (int j = 0; j < 4; j++) {
      int n = wn * 64 + j * 16 + lr;
      bfr[j] = *(const bf16x8*)((const char*)Bs + n * 64 + ((lq ^ ((n >> 1) & 3)) << 4));
    }
#pragma unroll
    for (int i = 0; i < 4; i++)
#pragma unroll
      for (int j = 0; j < 4; j++)
        acc[i][j] = __builtin_amdgcn_mfma_f32_16x16x32_bf16(af[i], bfr[j], acc[i][j], 0, 0, 0);
    __syncthreads();
  }

  // epilogue
  const bool do_stats = (accS != nullptr);
  if (do_stats) {
    if (tid < 128) { colS[tid] = 0.f; colQ[tid] = 0.f; }
    __syncthreads();
  }
  float badd[4];
  int cols[4];
#pragma unroll
  for (int j = 0; j < 4; j++) {
    int c = bn + wn * 64 + j * 16 + lr;
    cols[j] = c;
    badd[j] = bias[c] + addv[c];
  }
#pragma unroll
  for (int j = 0; j < 4; j++) {
    float s = 0.f, q = 0.f;
#pragma unroll
    for (int i = 0; i < 4; i++) {
      int rbase = bm + wm * 64 + i * 16 + lq * 4;
#pragma unroll
      for (int rg = 0; rg < 4; rg++) {
        float v = acc[i][j][rg] + badd[j];
        if (do_gelu) v = gelu_tanh(v);
        size_t off = (size_t)(rbase + rg) * 512 + cols[j];
        if (Cb) Cb[off] = f2bf(v);
        else Cf[off] = v;
        s += v; q += v * v;
      }
    }
    if (do_stats) {
      atomicAdd(&colS[wn * 64 + j * 16 + lr], s);
      atomicAdd(&colQ[wn * 64 + j * 16 + lr], q);
    }
  }
  if (do_stats) {
    __syncthreads();
    if (tid < 128) {
      atomicAdd(&accS[bn + tid], colS[tid]);
      atomicAdd(&accQ[bn + tid], colQ[tid]);
    }
  }
}

// ---------------------------------------------------------------------------
// Final row L2 normalization, in place over d_out (32768 rows x 512)
// ---------------------------------------------------------------------------
__global__ __launch_bounds__(256) void l2norm_kernel(float* __restrict__ out) {
  const int wave = blockIdx.x * 4 + (threadIdx.x >> 6);
  const int lane = threadIdx.x & 63;
  float* p = out + (size_t)wave * DDIM + lane * 4;
  float v[8];
  ld8(p, v);
  float ss = 0.f;
#pragma unroll
  for (int j = 0; j < 8; j++) ss += v[j] * v[j];
  ss = wave_sum(ss);
  const float inv = 1.0f / sqrtf(ss);
#pragma unroll
  for (int j = 0; j < 8; j++) v[j] *= inv;
  st8(p, v);
}

extern "C" void kernel_launch(void* const* d_in, const int* in_sizes, int n_in,
                              void* d_out, int out_size, void* d_ws, size_t ws_size,
                              hipStream_t stream) {
  const float* img     = (const float*)d_in[0];
  const float* txt     = (const float*)d_in[1];
  const float* wg_w1   = (const float*)d_in[2];
  const float* wg_b1   = (const float*)d_in[3];
  const float* wg_w2   = (const float*)d_in[4];
  const float* wg_b2   = (const float*)d_in[5];
  const float* conv_w  = (const float*)d_in[6];
  const float* conv_b  = (const float*)d_in[7];
  const float* mg_bn_g = (const float*)d_in[8];
  const float* mg_bn_b = (const float*)d_in[9];
  const float* mg_w    = (const float*)d_in[10];
  const float* mg_b    = (const float*)d_in[11];
  const float* ph_bn1_g= (const float*)d_in[12];
  const float* ph_bn1_b= (const float*)d_in[13];
  const float* ph_w1   = (const float*)d_in[14];
  const float* ph_b1   = (const float*)d_in[15];
  const float* ph_bn2_g= (const float*)d_in[16];
  const float* ph_bn2_b= (const float*)d_in[17];
  const float* ph_w2   = (const float*)d_in[18];
  const float* ph_b2   = (const float*)d_in[19];
  float* out = (float*)d_out;

  const size_t BD = (size_t)NROWS * DDIM;
  const size_t WSZ = 512 * 512;

  unsigned short* xbf   = (unsigned short*)d_ws;  // later reused as t1img bf16
  unsigned short* imgbf = xbf + BD;               // later reused as t1f bf16
  unsigned short* fusbf = imgbf + BD;
  unsigned short* Wt0   = fusbf + BD;
  unsigned short* Wt1   = Wt0 + WSZ;
  unsigned short* Wt2   = Wt1 + WSZ;
  unsigned short* Wt3   = Wt2 + WSZ;
  unsigned short* Wt4   = Wt3 + WSZ;
  float* acc  = (float*)(Wt4 + WSZ);   // 10*512 gemm stats
  float* addv = acc + 10 * 512;        // 5*512 shift-row terms
  float* accPart = addv + 5 * 512;     // 32 copies x 4 arrays x 512
  float* aff  = accPart + 32 * 2048;   // 10*512 affine params

  float* accFs = acc + 4 * 512, *accFq = acc + 5 * 512;
  float* accT1s= acc + 6 * 512, *accT1q= acc + 7 * 512;
  float* accT2s= acc + 8 * 512, *accT2q= acc + 9 * 512;
  float* add0 = addv + 0 * 512, *add1 = addv + 1 * 512, *add2 = addv + 2 * 512;
  float* add3 = addv + 3 * 512, *add4 = addv + 4 * 512;
  float* a0s = aff + 0 * 512, *a0h = aff + 1 * 512;
  float* a1s = aff + 2 * 512, *a1h = aff + 3 * 512;
  float* a2s = aff + 4 * 512, *a2h = aff + 5 * 512;
  float* a3s = aff + 6 * 512, *a3h = aff + 7 * 512;
  float* a4s = aff + 8 * 512, *a4h = aff + 9 * 512;

  // zero gemm-stats + addv + accPart in one memset (contiguous)
  hipMemsetAsync(acc, 0, (15 * 512 + 32 * 2048) * sizeof(float), stream);

  // prep emits xbf, imgbf, and 32-copy partial stats
  prep_kernel<<<2048, 256, 0, stream>>>(img, txt, wg_w1, wg_b1, wg_w2, wg_b2,
                                        conv_w, conv_b, xbf, imgbf, accPart);
  const float invM = 1.0f / (float)NROWS;
  // X stats: copies at accPart[c*2048 + {0,512}], I stats at {1024,1536}
  finalize_kernel<<<1, 512, 0, stream>>>(accPart + 0, accPart + 512,
                                         mg_bn_g, mg_bn_b, a0s, a0h, invM, 32, 2048);
  finalize_kernel<<<1, 512, 0, stream>>>(accPart + 1024, accPart + 1536,
                                         ph_bn1_g, ph_bn1_b, a1s, a1h, invM, 32, 2048);

  dim3 wgrid(16, 16);
  dim3 ggrid(NROWS / 128, DDIM / 128);

  wconv_kernel<<<wgrid, 256, 0, stream>>>(mg_w, a0s, a0h, Wt0, add0);
  // fused = gelu(BN0(x) @ mg_w + mg_b), stats(fused)
  gemm_bf16<<<ggrid, 256, 0, stream>>>(xbf, Wt0, mg_b, add0, nullptr, fusbf, 1, accFs, accFq);
  finalize_kernel<<<1, 512, 0, stream>>>(accFs, accFq, ph_bn1_g, ph_bn1_b, a2s, a2h, invM, 1, 0);

  wconv_kernel<<<wgrid, 256, 0, stream>>>(ph_w1, a1s, a1h, Wt1, add1);
  // t1_img = gelu(BN1(img) @ ph_w1 + ph_b1) -> reuse xbf buffer
  gemm_bf16<<<ggrid, 256, 0, stream>>>(imgbf, Wt1, ph_b1, add1, nullptr, xbf, 1, accT1s, accT1q);

  wconv_kernel<<<wgrid, 256, 0, stream>>>(ph_w1, a2s, a2h, Wt2, add2);
  // t1_fused = gelu(BN2(fused) @ ph_w1 + ph_b1) -> reuse imgbf buffer
  gemm_bf16<<<ggrid, 256, 0, stream>>>(fusbf, Wt2, ph_b1, add2, nullptr, imgbf, 1, accT2s, accT2q);

  finalize_kernel<<<1, 512, 0, stream>>>(accT1s, accT1q, ph_bn2_g, ph_bn2_b, a3s, a3h, invM, 1, 0);
  finalize_kernel<<<1, 512, 0, stream>>>(accT2s, accT2q, ph_bn2_g, ph_bn2_b, a4s, a4h, invM, 1, 0);

  wconv_kernel<<<wgrid, 256, 0, stream>>>(ph_w2, a3s, a3h, Wt3, add3);
  wconv_kernel<<<wgrid, 256, 0, stream>>>(ph_w2, a4s, a4h, Wt4, add4);

  // final projections straight into d_out halves (fp32, no activation)
  gemm_bf16<<<ggrid, 256, 0, stream>>>(xbf, Wt3, ph_b2, add3, out, nullptr, 0, nullptr, nullptr);
  gemm_bf16<<<ggrid, 256, 0, stream>>>(imgbf, Wt4, ph_b2, add4, out + BD, nullptr, 0, nullptr, nullptr);

  // row-wise L2 normalize both outputs in place
  l2norm_kernel<<<(2 * NROWS) / 4, 256, 0, stream>>>(out);
}

// Round 3
// 577.063 us; speedup vs baseline: 1.3093x; 1.3093x over previous
//
#include <hip/hip_runtime.h>
#include <cmath>

// Problem constants
#define NROWS 16384
#define DDIM  512

typedef __attribute__((ext_vector_type(8))) short          bf16x8;
typedef __attribute__((ext_vector_type(4))) float          f32x4;
typedef __attribute__((ext_vector_type(8))) unsigned short u16x8;
typedef __attribute__((ext_vector_type(4))) unsigned short u16x4;

__device__ __forceinline__ unsigned short f2bf(float f) {
  unsigned u = __float_as_uint(f);
  u += 0x7fffu + ((u >> 16) & 1u);  // RNE; inputs finite
  return (unsigned short)(u >> 16);
}

__device__ __forceinline__ float gelu_tanh(float x) {
  float x3 = x * x * x;
  float t = tanhf(0.79788456080286535588f * (x + 0.044715f * x3));
  return 0.5f * x * (1.0f + t);
}

__device__ __forceinline__ void ld8(const float* p, float* v) {
  float4 a = *(const float4*)p;
  float4 b = *(const float4*)(p + 256);
  v[0] = a.x; v[1] = a.y; v[2] = a.z; v[3] = a.w;
  v[4] = b.x; v[5] = b.y; v[6] = b.z; v[7] = b.w;
}

__device__ __forceinline__ void st8(float* p, const float* v) {
  *(float4*)p = make_float4(v[0], v[1], v[2], v[3]);
  *(float4*)(p + 256) = make_float4(v[4], v[5], v[6], v[7]);
}

__device__ __forceinline__ float wave_sum(float v) {
#pragma unroll
  for (int m = 1; m < 64; m <<= 1) v += __shfl_xor(v, m, 64);
  return v;
}

// ---------------------------------------------------------------------------
// Kernel 1: per-row prep. Gate numerics FROZEN (same fp64 chain, bit-identical:
// fp32 weights are converted to fp64 at use via exact v_cvt_f64_f32).
// Round-6: __launch_bounds__(256) ONLY — round 5's (256,4) cap forced VGPR=64
// and ~1 GB of scratch spill traffic (FETCH 461 MB / WRITE 553 MB). Natural
// allocation (~130 VGPR) never spills. Keep: 2048 blocks x 2 rows/wave,
// 32-copy spread atomics (64 adds/addr vs 2048), imgbf fold-in.
// ---------------------------------------------------------------------------
__global__ __launch_bounds__(256) void prep_kernel(
    const float* __restrict__ img, const float* __restrict__ txt,
    const float* __restrict__ wg_w1, const float* __restrict__ wg_b1,
    const float* __restrict__ wg_w2, const float* __restrict__ wg_b2,
    const float* __restrict__ conv_w, const float* __restrict__ conv_b,
    unsigned short* __restrict__ xbf, unsigned short* __restrict__ imgbf,
    float* __restrict__ accPart) {
  __shared__ float csX[512], cqX[512], csI[512], cqI[512];
  const int tid = threadIdx.x;
  for (int i = tid; i < 512; i += 256) {
    csX[i] = 0.f; cqX[i] = 0.f; csI[i] = 0.f; cqI[i] = 0.f;
  }
  __syncthreads();

  const int lane = tid & 63;
  const int gwave = blockIdx.x * 4 + (tid >> 6);  // 0..8191

  const float cb = conv_b[0];
  const float b2f = wg_b2[0];
  // keep as fp32 (uniform -> SGPRs); convert to fp64 at use (exact)
  float w1f[16], b1f[16], w2f[16];
#pragma unroll
  for (int i = 0; i < 16; i++) {
    w1f[i] = wg_w1[i]; b1f[i] = wg_b1[i]; w2f[i] = wg_w2[i];
  }
  float cw[5];
#pragma unroll
  for (int k = 0; k < 5; k++) cw[k] = conv_w[k];

  float sX[8] = {0, 0, 0, 0, 0, 0, 0, 0}, qX[8] = {0, 0, 0, 0, 0, 0, 0, 0};
  float sI[8] = {0, 0, 0, 0, 0, 0, 0, 0}, qI[8] = {0, 0, 0, 0, 0, 0, 0, 0};

  for (int it = 0; it < 2; it++) {
    const int r = gwave * 2 + it;
    const float* ip = img + (size_t)r * DDIM + lane * 4;
    float iv[8];
    ld8(ip, iv);
    double ss = 0.0;
#pragma unroll
    for (int j = 0; j < 8; j++) ss += (double)iv[j] * (double)iv[j];
#pragma unroll
    for (int m = 1; m < 64; m <<= 1) ss += __shfl_xor(ss, m, 64);
    const double dimg = fmax(sqrt(ss), 1e-12);

    // img -> bf16 (same f2bf rounding the old cvt_kernel used)
    {
      u16x4 lo, hi;
#pragma unroll
      for (int j = 0; j < 4; j++) { lo[j] = f2bf(iv[j]); hi[j] = f2bf(iv[4 + j]); }
      *(u16x4*)(imgbf + (size_t)r * DDIM + lane * 4) = lo;
      *(u16x4*)(imgbf + (size_t)r * DDIM + 256 + lane * 4) = hi;
    }

    float tv[5][8];
    double simv[5];
#pragma unroll
    for (int k = 0; k < 5; k++) {
      const float* tp = txt + ((size_t)r * 5 + k) * DDIM + lane * 4;
      ld8(tp, tv[k]);
      double s2 = 0.0, dp = 0.0;
#pragma unroll
      for (int j = 0; j < 8; j++) {
        s2 += (double)tv[k][j] * (double)tv[k][j];
        dp += (double)iv[j] * (double)tv[k][j];
      }
#pragma unroll
      for (int m = 1; m < 64; m <<= 1) {
        s2 += __shfl_xor(s2, m, 64);
        dp += __shfl_xor(dp, m, 64);
      }
      const double dt = fmax(sqrt(s2), 1e-12);
      simv[k] = dp / (dimg * dt);
    }

    // WeightGate logit in fp64 (true ordering), sigmoid emulating fp32 chain
    float wv[5];
#pragma unroll
    for (int k = 0; k < 5; k++) {
      double o = (double)b2f;
#pragma unroll
      for (int i = 0; i < 16; i++) {
        double h = simv[k] * (double)w1f[i] + (double)b1f[i];
        h = fmax(h, 0.0);
        o += h * (double)w2f[i];
      }
      float o32 = (float)o;
      float e32 = (float)exp(-(double)o32);  // correctly-rounded f32 exp
      float a32 = 1.0f + e32;
      wv[k] = 1.0f / a32;
    }

    // stable descending rank -> coefficient
    float c[5];
#pragma unroll
    for (int k = 0; k < 5; k++) {
      int rk = 0;
#pragma unroll
      for (int j = 0; j < 5; j++)
        rk += (int)((wv[j] > wv[k]) || ((wv[j] == wv[k]) && (j < k)));
      c[k] = cw[rk] * wv[k];
    }

    float xv[8];
#pragma unroll
    for (int j = 0; j < 8; j++) {
      float v = cb;
#pragma unroll
      for (int k = 0; k < 5; k++) v = fmaf(c[k], tv[k][j], v);
      xv[j] = v;
    }
    {
      u16x4 lo, hi;
#pragma unroll
      for (int j = 0; j < 4; j++) { lo[j] = f2bf(xv[j]); hi[j] = f2bf(xv[4 + j]); }
      *(u16x4*)(xbf + (size_t)r * DDIM + lane * 4) = lo;
      *(u16x4*)(xbf + (size_t)r * DDIM + 256 + lane * 4) = hi;
    }

#pragma unroll
    for (int j = 0; j < 8; j++) {
      sX[j] += xv[j]; qX[j] += xv[j] * xv[j];
      sI[j] += iv[j]; qI[j] += iv[j] * iv[j];
    }
  }

  const int c0 = lane * 4, c1 = 256 + lane * 4;
#pragma unroll
  for (int j = 0; j < 4; j++) {
    atomicAdd(&csX[c0 + j], sX[j]);     atomicAdd(&cqX[c0 + j], qX[j]);
    atomicAdd(&csX[c1 + j], sX[4 + j]); atomicAdd(&cqX[c1 + j], qX[4 + j]);
    atomicAdd(&csI[c0 + j], sI[j]);     atomicAdd(&cqI[c0 + j], qI[j]);
    atomicAdd(&csI[c1 + j], sI[4 + j]); atomicAdd(&cqI[c1 + j], qI[4 + j]);
  }
  __syncthreads();
  // 32-copy spread: [copy][{Xs,Xq,Is,Iq}][512]
  float* base = accPart + (size_t)(blockIdx.x & 31) * 2048;
  for (int i = tid; i < 512; i += 256) {
    atomicAdd(&base[i], csX[i]);
    atomicAdd(&base[512 + i], cqX[i]);
    atomicAdd(&base[1024 + i], csI[i]);
    atomicAdd(&base[1536 + i], cqI[i]);
  }
}

// ---------------------------------------------------------------------------
// finalize: (optionally multi-copy) BN stats -> affine
// scale = g*rstd, shift = b - mean*scale
// ---------------------------------------------------------------------------
__global__ void finalize_kernel(const float* __restrict__ s, const float* __restrict__ q,
                                const float* __restrict__ g, const float* __restrict__ b,
                                float* __restrict__ scale, float* __restrict__ shift,
                                float invM, int ncopies, int stride) {
  int j = threadIdx.x;
  if (j >= 512) return;
  float ss = 0.f, qq = 0.f;
  for (int c = 0; c < ncopies; c++) {
    ss += s[(size_t)c * stride + j];
    qq += q[(size_t)c * stride + j];
  }
  float m = ss * invM;
  float v = qq * invM - m * m;
  float r = 1.0f / sqrtf(v + 1e-5f);
  float sc = g[j] * r;
  scale[j] = sc;
  shift[j] = fmaf(-m, sc, b[j]);
}

// ---------------------------------------------------------------------------
// Weight prep: Wt[n][k] = bf16(scale[k] * W[k][n])  (transpose + fold BN scale)
//              addv[n] += sum_k shift[k] * W[k][n]  (exact fp32 shift term)
// grid (16,16), 32x32 tile per block.
// ---------------------------------------------------------------------------
__global__ __launch_bounds__(256) void wconv_kernel(
    const float* __restrict__ W, const float* __restrict__ scale,
    const float* __restrict__ shift, unsigned short* __restrict__ Wt,
    float* __restrict__ addv) {
  __shared__ float T[32][33];
  __shared__ float P[32];
  const int t = threadIdx.x;
  const int k0 = blockIdx.x * 32, n0 = blockIdx.y * 32;
  {
    int r = t >> 3, c = (t & 7) * 4;
    float4 v = *(const float4*)&W[(size_t)(k0 + r) * 512 + n0 + c];
    T[r][c] = v.x; T[r][c + 1] = v.y; T[r][c + 2] = v.z; T[r][c + 3] = v.w;
  }
  if (t < 32) P[t] = 0.f;
  __syncthreads();
  {
    int n = t >> 3, k = (t & 7) * 4;
    u16x4 o;
#pragma unroll
    for (int i = 0; i < 4; i++) o[i] = f2bf(T[k + i][n] * scale[k0 + k + i]);
    *(u16x4*)&Wt[(size_t)(n0 + n) * 512 + k0 + k] = o;
  }
  {
    int n = t & 31, rb = (t >> 5) * 4;
    float p = 0.f;
#pragma unroll
    for (int i = 0; i < 4; i++) p += shift[k0 + rb + i] * T[rb + i][n];
    atomicAdd(&P[n], p);
  }
  __syncthreads();
  if (t < 32) atomicAdd(&addv[n0 + t], P[t]);
}

// ---------------------------------------------------------------------------
// bf16 MFMA GEMM: C = act( A @ Wt^T + bias + addv ), A:[16384,512] bf16,
// Wt:[512,512] bf16 stored [n][k]. Tile 128x128, BK=32, 4 waves (2x2),
// 16x16x32 MFMA, 4x4 tiles/wave. LDS XOR-swizzle (kl ^= (row>>1)&3) makes
// ds_read_b128 frag loads conflict-free. Register-prefetched staging.
// Output: bf16 (Cb, feeds next GEMM) or fp32 (Cf, final). Optional col stats.
// ---------------------------------------------------------------------------
__global__ __launch_bounds__(256) void gemm_bf16(
    const unsigned short* __restrict__ A, const unsigned short* __restrict__ Wt,
    const float* __restrict__ bias, const float* __restrict__ addv,
    float* __restrict__ Cf, unsigned short* __restrict__ Cb, int do_gelu,
    float* __restrict__ accS, float* __restrict__ accQ) {
  __shared__ __align__(16) short As[128 * 32];
  __shared__ __align__(16) short Bs[128 * 32];
  __shared__ float colS[128], colQ[128];
  const int tid = threadIdx.x;
  const int ln = tid & 63;
  const int lq = ln >> 4, lr = ln & 15;
  const int wv = tid >> 6;
  const int wm = wv >> 1, wn = wv & 1;
  const int bm = blockIdx.x * 128, bn = blockIdx.y * 128;

  f32x4 acc[4][4];
#pragma unroll
  for (int i = 0; i < 4; i++)
#pragma unroll
    for (int j = 0; j < 4; j++) acc[i][j] = (f32x4){0.f, 0.f, 0.f, 0.f};

  // staging addresses: thread covers LDS 16B slots idx0, idx1 (512 slots/matrix)
  const int idx0 = tid, idx1 = 256 + tid;
  const int r0 = idx0 >> 2, k0g = (idx0 & 3) ^ ((r0 >> 1) & 3);
  const int r1 = idx1 >> 2, k1g = (idx1 & 3) ^ ((r1 >> 1) & 3);
  const unsigned short* ga0 = A + (size_t)(bm + r0) * 512 + k0g * 8;
  const unsigned short* ga1 = A + (size_t)(bm + r1) * 512 + k1g * 8;
  const unsigned short* gb0 = Wt + (size_t)(bn + r0) * 512 + k0g * 8;
  const unsigned short* gb1 = Wt + (size_t)(bn + r1) * 512 + k1g * 8;

  u16x8 va0 = *(const u16x8*)ga0, va1 = *(const u16x8*)ga1;
  u16x8 vb0 = *(const u16x8*)gb0, vb1 = *(const u16x8*)gb1;

  for (int kk = 0; kk < 512; kk += 32) {
    *(u16x8*)((char*)As + idx0 * 16) = va0;
    *(u16x8*)((char*)As + idx1 * 16) = va1;
    *(u16x8*)((char*)Bs + idx0 * 16) = vb0;
    *(u16x8*)((char*)Bs + idx1 * 16) = vb1;
    __syncthreads();
    if (kk + 32 < 512) {
      va0 = *(const u16x8*)(ga0 + kk + 32);
      va1 = *(const u16x8*)(ga1 + kk + 32);
      vb0 = *(const u16x8*)(gb0 + kk + 32);
      vb1 = *(const u16x8*)(gb1 + kk + 32);
    }
    bf16x8 af[4], bfr[4];
#pragma unroll
    for (int i = 0; i < 4; i++) {
      int r = wm * 64 + i * 16 + lr;
      af[i] = *(const bf16x8*)((const char*)As + r * 64 + ((lq ^ ((r >> 1) & 3)) << 4));
    }
#pragma unroll
    for (int j = 0; j < 4; j++) {
      int n = wn * 64 + j * 16 + lr;
      bfr[j] = *(const bf16x8*)((const char*)Bs + n * 64 + ((lq ^ ((n >> 1) & 3)) << 4));
    }
#pragma unroll
    for (int i = 0; i < 4; i++)
#pragma unroll
      for (int j = 0; j < 4; j++)
        acc[i][j] = __builtin_amdgcn_mfma_f32_16x16x32_bf16(af[i], bfr[j], acc[i][j], 0, 0, 0);
    __syncthreads();
  }

  // epilogue
  const bool do_stats = (accS != nullptr);
  if (do_stats) {
    if (tid < 128) { colS[tid] = 0.f; colQ[tid] = 0.f; }
    __syncthreads();
  }
  float badd[4];
  int cols[4];
#pragma unroll
  for (int j = 0; j < 4; j++) {
    int c = bn + wn * 64 + j * 16 + lr;
    cols[j] = c;
    badd[j] = bias[c] + addv[c];
  }
#pragma unroll
  for (int j = 0; j < 4; j++) {
    float s = 0.f, q = 0.f;
#pragma unroll
    for (int i = 0; i < 4; i++) {
      int rbase = bm + wm * 64 + i * 16 + lq * 4;
#pragma unroll
      for (int rg = 0; rg < 4; rg++) {
        float v = acc[i][j][rg] + badd[j];
        if (do_gelu) v = gelu_tanh(v);
        size_t off = (size_t)(rbase + rg) * 512 + cols[j];
        if (Cb) Cb[off] = f2bf(v);
        else Cf[off] = v;
        s += v; q += v * v;
      }
    }
    if (do_stats) {
      atomicAdd(&colS[wn * 64 + j * 16 + lr], s);
      atomicAdd(&colQ[wn * 64 + j * 16 + lr], q);
    }
  }
  if (do_stats) {
    __syncthreads();
    if (tid < 128) {
      atomicAdd(&accS[bn + tid], colS[tid]);
      atomicAdd(&accQ[bn + tid], colQ[tid]);
    }
  }
}

// ---------------------------------------------------------------------------
// Final row L2 normalization, in place over d_out (32768 rows x 512)
// ---------------------------------------------------------------------------
__global__ __launch_bounds__(256) void l2norm_kernel(float* __restrict__ out) {
  const int wave = blockIdx.x * 4 + (threadIdx.x >> 6);
  const int lane = threadIdx.x & 63;
  float* p = out + (size_t)wave * DDIM + lane * 4;
  float v[8];
  ld8(p, v);
  float ss = 0.f;
#pragma unroll
  for (int j = 0; j < 8; j++) ss += v[j] * v[j];
  ss = wave_sum(ss);
  const float inv = 1.0f / sqrtf(ss);
#pragma unroll
  for (int j = 0; j < 8; j++) v[j] *= inv;
  st8(p, v);
}

extern "C" void kernel_launch(void* const* d_in, const int* in_sizes, int n_in,
                              void* d_out, int out_size, void* d_ws, size_t ws_size,
                              hipStream_t stream) {
  const float* img     = (const float*)d_in[0];
  const float* txt     = (const float*)d_in[1];
  const float* wg_w1   = (const float*)d_in[2];
  const float* wg_b1   = (const float*)d_in[3];
  const float* wg_w2   = (const float*)d_in[4];
  const float* wg_b2   = (const float*)d_in[5];
  const float* conv_w  = (const float*)d_in[6];
  const float* conv_b  = (const float*)d_in[7];
  const float* mg_bn_g = (const float*)d_in[8];
  const float* mg_bn_b = (const float*)d_in[9];
  const float* mg_w    = (const float*)d_in[10];
  const float* mg_b    = (const float*)d_in[11];
  const float* ph_bn1_g= (const float*)d_in[12];
  const float* ph_bn1_b= (const float*)d_in[13];
  const float* ph_w1   = (const float*)d_in[14];
  const float* ph_b1   = (const float*)d_in[15];
  const float* ph_bn2_g= (const float*)d_in[16];
  const float* ph_bn2_b= (const float*)d_in[17];
  const float* ph_w2   = (const float*)d_in[18];
  const float* ph_b2   = (const float*)d_in[19];
  float* out = (float*)d_out;

  const size_t BD = (size_t)NROWS * DDIM;
  const size_t WSZ = 512 * 512;

  unsigned short* xbf   = (unsigned short*)d_ws;  // later reused as t1img bf16
  unsigned short* imgbf = xbf + BD;               // later reused as t1f bf16
  unsigned short* fusbf = imgbf + BD;
  unsigned short* Wt0   = fusbf + BD;
  unsigned short* Wt1   = Wt0 + WSZ;
  unsigned short* Wt2   = Wt1 + WSZ;
  unsigned short* Wt3   = Wt2 + WSZ;
  unsigned short* Wt4   = Wt3 + WSZ;
  float* acc  = (float*)(Wt4 + WSZ);   // 10*512 gemm stats
  float* addv = acc + 10 * 512;        // 5*512 shift-row terms
  float* accPart = addv + 5 * 512;     // 32 copies x 4 arrays x 512
  float* aff  = accPart + 32 * 2048;   // 10*512 affine params

  float* accFs = acc + 4 * 512, *accFq = acc + 5 * 512;
  float* accT1s= acc + 6 * 512, *accT1q= acc + 7 * 512;
  float* accT2s= acc + 8 * 512, *accT2q= acc + 9 * 512;
  float* add0 = addv + 0 * 512, *add1 = addv + 1 * 512, *add2 = addv + 2 * 512;
  float* add3 = addv + 3 * 512, *add4 = addv + 4 * 512;
  float* a0s = aff + 0 * 512, *a0h = aff + 1 * 512;
  float* a1s = aff + 2 * 512, *a1h = aff + 3 * 512;
  float* a2s = aff + 4 * 512, *a2h = aff + 5 * 512;
  float* a3s = aff + 6 * 512, *a3h = aff + 7 * 512;
  float* a4s = aff + 8 * 512, *a4h = aff + 9 * 512;

  // zero gemm-stats + addv + accPart in one memset (contiguous)
  hipMemsetAsync(acc, 0, (15 * 512 + 32 * 2048) * sizeof(float), stream);

  // prep emits xbf, imgbf, and 32-copy partial stats
  prep_kernel<<<2048, 256, 0, stream>>>(img, txt, wg_w1, wg_b1, wg_w2, wg_b2,
                                        conv_w, conv_b, xbf, imgbf, accPart);
  const float invM = 1.0f / (float)NROWS;
  // X stats: copies at accPart[c*2048 + {0,512}], I stats at {1024,1536}
  finalize_kernel<<<1, 512, 0, stream>>>(accPart + 0, accPart + 512,
                                         mg_bn_g, mg_bn_b, a0s, a0h, invM, 32, 2048);
  finalize_kernel<<<1, 512, 0, stream>>>(accPart + 1024, accPart + 1536,
                                         ph_bn1_g, ph_bn1_b, a1s, a1h, invM, 32, 2048);

  dim3 wgrid(16, 16);
  dim3 ggrid(NROWS / 128, DDIM / 128);

  wconv_kernel<<<wgrid, 256, 0, stream>>>(mg_w, a0s, a0h, Wt0, add0);
  // fused = gelu(BN0(x) @ mg_w + mg_b), stats(fused)
  gemm_bf16<<<ggrid, 256, 0, stream>>>(xbf, Wt0, mg_b, add0, nullptr, fusbf, 1, accFs, accFq);
  finalize_kernel<<<1, 512, 0, stream>>>(accFs, accFq, ph_bn1_g, ph_bn1_b, a2s, a2h, invM, 1, 0);

  wconv_kernel<<<wgrid, 256, 0, stream>>>(ph_w1, a1s, a1h, Wt1, add1);
  // t1_img = gelu(BN1(img) @ ph_w1 + ph_b1) -> reuse xbf buffer
  gemm_bf16<<<ggrid, 256, 0, stream>>>(imgbf, Wt1, ph_b1, add1, nullptr, xbf, 1, accT1s, accT1q);

  wconv_kernel<<<wgrid, 256, 0, stream>>>(ph_w1, a2s, a2h, Wt2, add2);
  // t1_fused = gelu(BN2(fused) @ ph_w1 + ph_b1) -> reuse imgbf buffer
  gemm_bf16<<<ggrid, 256, 0, stream>>>(fusbf, Wt2, ph_b1, add2, nullptr, imgbf, 1, accT2s, accT2q);

  finalize_kernel<<<1, 512, 0, stream>>>(accT1s, accT1q, ph_bn2_g, ph_bn2_b, a3s, a3h, invM, 1, 0);
  finalize_kernel<<<1, 512, 0, stream>>>(accT2s, accT2q, ph_bn2_g, ph_bn2_b, a4s, a4h, invM, 1, 0);

  wconv_kernel<<<wgrid, 256, 0, stream>>>(ph_w2, a3s, a3h, Wt3, add3);
  wconv_kernel<<<wgrid, 256, 0, stream>>>(ph_w2, a4s, a4h, Wt4, add4);

  // final projections straight into d_out halves (fp32, no activation)
  gemm_bf16<<<ggrid, 256, 0, stream>>>(xbf, Wt3, ph_b2, add3, out, nullptr, 0, nullptr, nullptr);
  gemm_bf16<<<ggrid, 256, 0, stream>>>(imgbf, Wt4, ph_b2, add4, out + BD, nullptr, 0, nullptr, nullptr);

  // row-wise L2 normalize both outputs in place
  l2norm_kernel<<<(2 * NROWS) / 4, 256, 0, stream>>>(out);
}

// Round 4
// 521.235 us; speedup vs baseline: 1.4495x; 1.1071x over previous
//
#include <hip/hip_runtime.h>
#include <cmath>

// Problem constants
#define NROWS 16384
#define DDIM  512

typedef __attribute__((ext_vector_type(8))) short          bf16x8;
typedef __attribute__((ext_vector_type(4))) float          f32x4;
typedef __attribute__((ext_vector_type(8))) unsigned short u16x8;
typedef __attribute__((ext_vector_type(4))) unsigned short u16x4;

__device__ __forceinline__ unsigned short f2bf(float f) {
  unsigned u = __float_as_uint(f);
  u += 0x7fffu + ((u >> 16) & 1u);  // RNE; inputs finite
  return (unsigned short)(u >> 16);
}

__device__ __forceinline__ float gelu_tanh(float x) {
  float x3 = x * x * x;
  float t = tanhf(0.79788456080286535588f * (x + 0.044715f * x3));
  return 0.5f * x * (1.0f + t);
}

__device__ __forceinline__ void ld8(const float* p, float* v) {
  float4 a = *(const float4*)p;
  float4 b = *(const float4*)(p + 256);
  v[0] = a.x; v[1] = a.y; v[2] = a.z; v[3] = a.w;
  v[4] = b.x; v[5] = b.y; v[6] = b.z; v[7] = b.w;
}

__device__ __forceinline__ void st8(float* p, const float* v) {
  *(float4*)p = make_float4(v[0], v[1], v[2], v[3]);
  *(float4*)(p + 256) = make_float4(v[4], v[5], v[6], v[7]);
}

__device__ __forceinline__ float wave_sum(float v) {
#pragma unroll
  for (int m = 1; m < 64; m <<= 1) v += __shfl_xor(v, m, 64);
  return v;
}

// ---------------------------------------------------------------------------
// Kernel 1: per-row prep. Gate numerics FROZEN — bit-identical restructure:
// every accumulator keeps its exact add order (same m/j/i sequences, same
// expression forms); only instruction-level parallelism is exposed.
// Round-7 (evidence: r0 512blk=132us < r3 2048blk=179us at same VGPR/occ ->
// per-block prologue is heavy; VALUBusy 16% w/ 3 waves/SIMD -> latency-bound
// on 11 SERIAL fp64 butterfly reductions per row):
//   - back to 512 blocks x 8 rows/wave (best prologue amortization)
//   - all 11 reductions (ss, s2[5], dp[5]) interleaved in ONE butterfly loop
//   - 8-elem fp64 partial sums interleaved in ONE j-loop
//   - gate MLP i-outer/k-inner (5-way ILP on the 16-deep fp64 chain)
//   - keep: 32-copy spread atomics, imgbf fold-in, fp32 weight residency
// ---------------------------------------------------------------------------
__global__ __launch_bounds__(256) void prep_kernel(
    const float* __restrict__ img, const float* __restrict__ txt,
    const float* __restrict__ wg_w1, const float* __restrict__ wg_b1,
    const float* __restrict__ wg_w2, const float* __restrict__ wg_b2,
    const float* __restrict__ conv_w, const float* __restrict__ conv_b,
    unsigned short* __restrict__ xbf, unsigned short* __restrict__ imgbf,
    float* __restrict__ accPart) {
  __shared__ float csX[512], cqX[512], csI[512], cqI[512];
  const int tid = threadIdx.x;
  for (int i = tid; i < 512; i += 256) {
    csX[i] = 0.f; cqX[i] = 0.f; csI[i] = 0.f; cqI[i] = 0.f;
  }
  __syncthreads();

  const int lane = tid & 63;
  const int gwave = blockIdx.x * 4 + (tid >> 6);  // 0..2047

  const float cb = conv_b[0];
  const float b2f = wg_b2[0];
  // fp32 (uniform -> SGPRs); convert to fp64 at use (exact)
  float w1f[16], b1f[16], w2f[16];
#pragma unroll
  for (int i = 0; i < 16; i++) {
    w1f[i] = wg_w1[i]; b1f[i] = wg_b1[i]; w2f[i] = wg_w2[i];
  }
  float cw[5];
#pragma unroll
  for (int k = 0; k < 5; k++) cw[k] = conv_w[k];

  float sX[8] = {0, 0, 0, 0, 0, 0, 0, 0}, qX[8] = {0, 0, 0, 0, 0, 0, 0, 0};
  float sI[8] = {0, 0, 0, 0, 0, 0, 0, 0}, qI[8] = {0, 0, 0, 0, 0, 0, 0, 0};

  for (int it = 0; it < 8; it++) {
    const int r = gwave * 8 + it;
    const float* ip = img + (size_t)r * DDIM + lane * 4;
    float iv[8];
    ld8(ip, iv);

    // img -> bf16 early (fire-and-forget), + image stats (iv dead after loop)
    {
      u16x4 lo, hi;
#pragma unroll
      for (int j = 0; j < 4; j++) { lo[j] = f2bf(iv[j]); hi[j] = f2bf(iv[4 + j]); }
      *(u16x4*)(imgbf + (size_t)r * DDIM + lane * 4) = lo;
      *(u16x4*)(imgbf + (size_t)r * DDIM + 256 + lane * 4) = hi;
    }
#pragma unroll
    for (int j = 0; j < 8; j++) { sI[j] += iv[j]; qI[j] += iv[j] * iv[j]; }

    // load all 5 text rows first (loads in flight together)
    float tv[5][8];
#pragma unroll
    for (int k = 0; k < 5; k++)
      ld8(txt + ((size_t)r * 5 + k) * DDIM + lane * 4, tv[k]);

    // interleaved fp64 partial sums: each accumulator's j-order unchanged
    double ss = 0.0;
    double s2[5], dp[5];
#pragma unroll
    for (int k = 0; k < 5; k++) { s2[k] = 0.0; dp[k] = 0.0; }
#pragma unroll
    for (int j = 0; j < 8; j++) {
      ss += (double)iv[j] * (double)iv[j];
#pragma unroll
      for (int k = 0; k < 5; k++) {
        s2[k] += (double)tv[k][j] * (double)tv[k][j];
        dp[k] += (double)iv[j] * (double)tv[k][j];
      }
    }

    // ONE butterfly loop: 11 independent reductions interleave (same m order
    // per reduction as before -> bit-identical sums)
#pragma unroll
    for (int m = 1; m < 64; m <<= 1) {
      ss += __shfl_xor(ss, m, 64);
#pragma unroll
      for (int k = 0; k < 5; k++) {
        s2[k] += __shfl_xor(s2[k], m, 64);
        dp[k] += __shfl_xor(dp[k], m, 64);
      }
    }
    const double dimg = fmax(sqrt(ss), 1e-12);

    double simv[5];
#pragma unroll
    for (int k = 0; k < 5; k++) {
      const double dt = fmax(sqrt(s2[k]), 1e-12);
      simv[k] = dp[k] / (dimg * dt);
    }

    // WeightGate: i-outer/k-inner -> 5-way ILP; per-k accumulation order over
    // i unchanged (o[k] = b2 + sum_i ...), same expression forms
    double o[5];
#pragma unroll
    for (int k = 0; k < 5; k++) o[k] = (double)b2f;
#pragma unroll
    for (int i = 0; i < 16; i++) {
      const double w1d = (double)w1f[i];
      const double b1d = (double)b1f[i];
      const double w2d = (double)w2f[i];
#pragma unroll
      for (int k = 0; k < 5; k++) {
        double h = simv[k] * w1d + b1d;
        h = fmax(h, 0.0);
        o[k] += h * w2d;
      }
    }
    float wv[5];
#pragma unroll
    for (int k = 0; k < 5; k++) {
      float o32 = (float)o[k];
      float e32 = (float)exp(-(double)o32);  // correctly-rounded f32 exp
      float a32 = 1.0f + e32;
      wv[k] = 1.0f / a32;
    }

    // stable descending rank -> coefficient
    float c[5];
#pragma unroll
    for (int k = 0; k < 5; k++) {
      int rk = 0;
#pragma unroll
      for (int j = 0; j < 5; j++)
        rk += (int)((wv[j] > wv[k]) || ((wv[j] == wv[k]) && (j < k)));
      c[k] = cw[rk] * wv[k];
    }

    float xv[8];
#pragma unroll
    for (int j = 0; j < 8; j++) {
      float v = cb;
#pragma unroll
      for (int k = 0; k < 5; k++) v = fmaf(c[k], tv[k][j], v);
      xv[j] = v;
    }
    {
      u16x4 lo, hi;
#pragma unroll
      for (int j = 0; j < 4; j++) { lo[j] = f2bf(xv[j]); hi[j] = f2bf(xv[4 + j]); }
      *(u16x4*)(xbf + (size_t)r * DDIM + lane * 4) = lo;
      *(u16x4*)(xbf + (size_t)r * DDIM + 256 + lane * 4) = hi;
    }

#pragma unroll
    for (int j = 0; j < 8; j++) { sX[j] += xv[j]; qX[j] += xv[j] * xv[j]; }
  }

  const int c0 = lane * 4, c1 = 256 + lane * 4;
#pragma unroll
  for (int j = 0; j < 4; j++) {
    atomicAdd(&csX[c0 + j], sX[j]);     atomicAdd(&cqX[c0 + j], qX[j]);
    atomicAdd(&csX[c1 + j], sX[4 + j]); atomicAdd(&cqX[c1 + j], qX[4 + j]);
    atomicAdd(&csI[c0 + j], sI[j]);     atomicAdd(&cqI[c0 + j], qI[j]);
    atomicAdd(&csI[c1 + j], sI[4 + j]); atomicAdd(&cqI[c1 + j], qI[4 + j]);
  }
  __syncthreads();
  // 32-copy spread: [copy][{Xs,Xq,Is,Iq}][512]
  float* base = accPart + (size_t)(blockIdx.x & 31) * 2048;
  for (int i = tid; i < 512; i += 256) {
    atomicAdd(&base[i], csX[i]);
    atomicAdd(&base[512 + i], cqX[i]);
    atomicAdd(&base[1024 + i], csI[i]);
    atomicAdd(&base[1536 + i], cqI[i]);
  }
}

// ---------------------------------------------------------------------------
// finalize: (optionally multi-copy) BN stats -> affine
// scale = g*rstd, shift = b - mean*scale
// ---------------------------------------------------------------------------
__global__ void finalize_kernel(const float* __restrict__ s, const float* __restrict__ q,
                                const float* __restrict__ g, const float* __restrict__ b,
                                float* __restrict__ scale, float* __restrict__ shift,
                                float invM, int ncopies, int stride) {
  int j = threadIdx.x;
  if (j >= 512) return;
  float ss = 0.f, qq = 0.f;
  for (int c = 0; c < ncopies; c++) {
    ss += s[(size_t)c * stride + j];
    qq += q[(size_t)c * stride + j];
  }
  float m = ss * invM;
  float v = qq * invM - m * m;
  float r = 1.0f / sqrtf(v + 1e-5f);
  float sc = g[j] * r;
  scale[j] = sc;
  shift[j] = fmaf(-m, sc, b[j]);
}

// ---------------------------------------------------------------------------
// Weight prep: Wt[n][k] = bf16(scale[k] * W[k][n])  (transpose + fold BN scale)
//              addv[n] += sum_k shift[k] * W[k][n]  (exact fp32 shift term)
// grid (16,16), 32x32 tile per block.
// ---------------------------------------------------------------------------
__global__ __launch_bounds__(256) void wconv_kernel(
    const float* __restrict__ W, const float* __restrict__ scale,
    const float* __restrict__ shift, unsigned short* __restrict__ Wt,
    float* __restrict__ addv) {
  __shared__ float T[32][33];
  __shared__ float P[32];
  const int t = threadIdx.x;
  const int k0 = blockIdx.x * 32, n0 = blockIdx.y * 32;
  {
    int r = t >> 3, c = (t & 7) * 4;
    float4 v = *(const float4*)&W[(size_t)(k0 + r) * 512 + n0 + c];
    T[r][c] = v.x; T[r][c + 1] = v.y; T[r][c + 2] = v.z; T[r][c + 3] = v.w;
  }
  if (t < 32) P[t] = 0.f;
  __syncthreads();
  {
    int n = t >> 3, k = (t & 7) * 4;
    u16x4 o;
#pragma unroll
    for (int i = 0; i < 4; i++) o[i] = f2bf(T[k + i][n] * scale[k0 + k + i]);
    *(u16x4*)&Wt[(size_t)(n0 + n) * 512 + k0 + k] = o;
  }
  {
    int n = t & 31, rb = (t >> 5) * 4;
    float p = 0.f;
#pragma unroll
    for (int i = 0; i < 4; i++) p += shift[k0 + rb + i] * T[rb + i][n];
    atomicAdd(&P[n], p);
  }
  __syncthreads();
  if (t < 32) atomicAdd(&addv[n0 + t], P[t]);
}

// ---------------------------------------------------------------------------
// bf16 MFMA GEMM: C = act( A @ Wt^T + bias + addv ), A:[16384,512] bf16,
// Wt:[512,512] bf16 stored [n][k]. Tile 128x128, BK=32, 4 waves (2x2),
// 16x16x32 MFMA, 4x4 tiles/wave. LDS XOR-swizzle (kl ^= (row>>1)&3) makes
// ds_read_b128 frag loads conflict-free. Register-prefetched staging.
// Output: bf16 (Cb, feeds next GEMM) or fp32 (Cf, final). Optional col stats.
// ---------------------------------------------------------------------------
__global__ __launch_bounds__(256) void gemm_bf16(
    const unsigned short* __restrict__ A, const unsigned short* __restrict__ Wt,
    const float* __restrict__ bias, const float* __restrict__ addv,
    float* __restrict__ Cf, unsigned short* __restrict__ Cb, int do_gelu,
    float* __restrict__ accS, float* __restrict__ accQ) {
  __shared__ __align__(16) short As[128 * 32];
  __shared__ __align__(16) short Bs[128 * 32];
  __shared__ float colS[128], colQ[128];
  const int tid = threadIdx.x;
  const int ln = tid & 63;
  const int lq = ln >> 4, lr = ln & 15;
  const int wv = tid >> 6;
  const int wm = wv >> 1, wn = wv & 1;
  const int bm = blockIdx.x * 128, bn = blockIdx.y * 128;

  f32x4 acc[4][4];
#pragma unroll
  for (int i = 0; i < 4; i++)
#pragma unroll
    for (int j = 0; j < 4; j++) acc[i][j] = (f32x4){0.f, 0.f, 0.f, 0.f};

  // staging addresses: thread covers LDS 16B slots idx0, idx1 (512 slots/matrix)
  const int idx0 = tid, idx1 = 256 + tid;
  const int r0 = idx0 >> 2, k0g = (idx0 & 3) ^ ((r0 >> 1) & 3);
  const int r1 = idx1 >> 2, k1g = (idx1 & 3) ^ ((r1 >> 1) & 3);
  const unsigned short* ga0 = A + (size_t)(bm + r0) * 512 + k0g * 8;
  const unsigned short* ga1 = A + (size_t)(bm + r1) * 512 + k1g * 8;
  const unsigned short* gb0 = Wt + (size_t)(bn + r0) * 512 + k0g * 8;
  const unsigned short* gb1 = Wt + (size_t)(bn + r1) * 512 + k1g * 8;

  u16x8 va0 = *(const u16x8*)ga0, va1 = *(const u16x8*)ga1;
  u16x8 vb0 = *(const u16x8*)gb0, vb1 = *(const u16x8*)gb1;

  for (int kk = 0; kk < 512; kk += 32) {
    *(u16x8*)((char*)As + idx0 * 16) = va0;
    *(u16x8*)((char*)As + idx1 * 16) = va1;
    *(u16x8*)((char*)Bs + idx0 * 16) = vb0;
    *(u16x8*)((char*)Bs + idx1 * 16) = vb1;
    __syncthreads();
    if (kk + 32 < 512) {
      va0 = *(const u16x8*)(ga0 + kk + 32);
      va1 = *(const u16x8*)(ga1 + kk + 32);
      vb0 = *(const u16x8*)(gb0 + kk + 32);
      vb1 = *(const u16x8*)(gb1 + kk + 32);
    }
    bf16x8 af[4], bfr[4];
#pragma unroll
    for (int i = 0; i < 4; i++) {
      int r = wm * 64 + i * 16 + lr;
      af[i] = *(const bf16x8*)((const char*)As + r * 64 + ((lq ^ ((r >> 1) & 3)) << 4));
    }
#pragma unroll
    for (int j = 0; j < 4; j++) {
      int n = wn * 64 + j * 16 + lr;
      bfr[j] = *(const bf16x8*)((const char*)Bs + n * 64 + ((lq ^ ((n >> 1) & 3)) << 4));
    }
#pragma unroll
    for (int i = 0; i < 4; i++)
#pragma unroll
      for (int j = 0; j < 4; j++)
        acc[i][j] = __builtin_amdgcn_mfma_f32_16x16x32_bf16(af[i], bfr[j], acc[i][j], 0, 0, 0);
    __syncthreads();
  }

  // epilogue
  const bool do_stats = (accS != nullptr);
  if (do_stats) {
    if (tid < 128) { colS[tid] = 0.f; colQ[tid] = 0.f; }
    __syncthreads();
  }
  float badd[4];
  int cols[4];
#pragma unroll
  for (int j = 0; j < 4; j++) {
    int c = bn + wn * 64 + j * 16 + lr;
    cols[j] = c;
    badd[j] = bias[c] + addv[c];
  }
#pragma unroll
  for (int j = 0; j < 4; j++) {
    float s = 0.f, q = 0.f;
#pragma unroll
    for (int i = 0; i < 4; i++) {
      int rbase = bm + wm * 64 + i * 16 + lq * 4;
#pragma unroll
      for (int rg = 0; rg < 4; rg++) {
        float v = acc[i][j][rg] + badd[j];
        if (do_gelu) v = gelu_tanh(v);
        size_t off = (size_t)(rbase + rg) * 512 + cols[j];
        if (Cb) Cb[off] = f2bf(v);
        else Cf[off] = v;
        s += v; q += v * v;
      }
    }
    if (do_stats) {
      atomicAdd(&colS[wn * 64 + j * 16 + lr], s);
      atomicAdd(&colQ[wn * 64 + j * 16 + lr], q);
    }
  }
  if (do_stats) {
    __syncthreads();
    if (tid < 128) {
      atomicAdd(&accS[bn + tid], colS[tid]);
      atomicAdd(&accQ[bn + tid], colQ[tid]);
    }
  }
}

// ---------------------------------------------------------------------------
// Final row L2 normalization, in place over d_out (32768 rows x 512)
// ---------------------------------------------------------------------------
__global__ __launch_bounds__(256) void l2norm_kernel(float* __restrict__ out) {
  const int wave = blockIdx.x * 4 + (threadIdx.x >> 6);
  const int lane = threadIdx.x & 63;
  float* p = out + (size_t)wave * DDIM + lane * 4;
  float v[8];
  ld8(p, v);
  float ss = 0.f;
#pragma unroll
  for (int j = 0; j < 8; j++) ss += v[j] * v[j];
  ss = wave_sum(ss);
  const float inv = 1.0f / sqrtf(ss);
#pragma unroll
  for (int j = 0; j < 8; j++) v[j] *= inv;
  st8(p, v);
}

extern "C" void kernel_launch(void* const* d_in, const int* in_sizes, int n_in,
                              void* d_out, int out_size, void* d_ws, size_t ws_size,
                              hipStream_t stream) {
  const float* img     = (const float*)d_in[0];
  const float* txt     = (const float*)d_in[1];
  const float* wg_w1   = (const float*)d_in[2];
  const float* wg_b1   = (const float*)d_in[3];
  const float* wg_w2   = (const float*)d_in[4];
  const float* wg_b2   = (const float*)d_in[5];
  const float* conv_w  = (const float*)d_in[6];
  const float* conv_b  = (const float*)d_in[7];
  const float* mg_bn_g = (const float*)d_in[8];
  const float* mg_bn_b = (const float*)d_in[9];
  const float* mg_w    = (const float*)d_in[10];
  const float* mg_b    = (const float*)d_in[11];
  const float* ph_bn1_g= (const float*)d_in[12];
  const float* ph_bn1_b= (const float*)d_in[13];
  const float* ph_w1   = (const float*)d_in[14];
  const float* ph_b1   = (const float*)d_in[15];
  const float* ph_bn2_g= (const float*)d_in[16];
  const float* ph_bn2_b= (const float*)d_in[17];
  const float* ph_w2   = (const float*)d_in[18];
  const float* ph_b2   = (const float*)d_in[19];
  float* out = (float*)d_out;

  const size_t BD = (size_t)NROWS * DDIM;
  const size_t WSZ = 512 * 512;

  unsigned short* xbf   = (unsigned short*)d_ws;  // later reused as t1img bf16
  unsigned short* imgbf = xbf + BD;               // later reused as t1f bf16
  unsigned short* fusbf = imgbf + BD;
  unsigned short* Wt0   = fusbf + BD;
  unsigned short* Wt1   = Wt0 + WSZ;
  unsigned short* Wt2   = Wt1 + WSZ;
  unsigned short* Wt3   = Wt2 + WSZ;
  unsigned short* Wt4   = Wt3 + WSZ;
  float* acc  = (float*)(Wt4 + WSZ);   // 10*512 gemm stats
  float* addv = acc + 10 * 512;        // 5*512 shift-row terms
  float* accPart = addv + 5 * 512;     // 32 copies x 4 arrays x 512
  float* aff  = accPart + 32 * 2048;   // 10*512 affine params

  float* accFs = acc + 4 * 512, *accFq = acc + 5 * 512;
  float* accT1s= acc + 6 * 512, *accT1q= acc + 7 * 512;
  float* accT2s= acc + 8 * 512, *accT2q= acc + 9 * 512;
  float* add0 = addv + 0 * 512, *add1 = addv + 1 * 512, *add2 = addv + 2 * 512;
  float* add3 = addv + 3 * 512, *add4 = addv + 4 * 512;
  float* a0s = aff + 0 * 512, *a0h = aff + 1 * 512;
  float* a1s = aff + 2 * 512, *a1h = aff + 3 * 512;
  float* a2s = aff + 4 * 512, *a2h = aff + 5 * 512;
  float* a3s = aff + 6 * 512, *a3h = aff + 7 * 512;
  float* a4s = aff + 8 * 512, *a4h = aff + 9 * 512;

  // zero gemm-stats + addv + accPart in one memset (contiguous)
  hipMemsetAsync(acc, 0, (15 * 512 + 32 * 2048) * sizeof(float), stream);

  // prep emits xbf, imgbf, and 32-copy partial stats
  prep_kernel<<<512, 256, 0, stream>>>(img, txt, wg_w1, wg_b1, wg_w2, wg_b2,
                                       conv_w, conv_b, xbf, imgbf, accPart);
  const float invM = 1.0f / (float)NROWS;
  // X stats: copies at accPart[c*2048 + {0,512}], I stats at {1024,1536}
  finalize_kernel<<<1, 512, 0, stream>>>(accPart + 0, accPart + 512,
                                         mg_bn_g, mg_bn_b, a0s, a0h, invM, 32, 2048);
  finalize_kernel<<<1, 512, 0, stream>>>(accPart + 1024, accPart + 1536,
                                         ph_bn1_g, ph_bn1_b, a1s, a1h, invM, 32, 2048);

  dim3 wgrid(16, 16);
  dim3 ggrid(NROWS / 128, DDIM / 128);

  wconv_kernel<<<wgrid, 256, 0, stream>>>(mg_w, a0s, a0h, Wt0, add0);
  // fused = gelu(BN0(x) @ mg_w + mg_b), stats(fused)
  gemm_bf16<<<ggrid, 256, 0, stream>>>(xbf, Wt0, mg_b, add0, nullptr, fusbf, 1, accFs, accFq);
  finalize_kernel<<<1, 512, 0, stream>>>(accFs, accFq, ph_bn1_g, ph_bn1_b, a2s, a2h, invM, 1, 0);

  wconv_kernel<<<wgrid, 256, 0, stream>>>(ph_w1, a1s, a1h, Wt1, add1);
  // t1_img = gelu(BN1(img) @ ph_w1 + ph_b1) -> reuse xbf buffer
  gemm_bf16<<<ggrid, 256, 0, stream>>>(imgbf, Wt1, ph_b1, add1, nullptr, xbf, 1, accT1s, accT1q);

  wconv_kernel<<<wgrid, 256, 0, stream>>>(ph_w1, a2s, a2h, Wt2, add2);
  // t1_fused = gelu(BN2(fused) @ ph_w1 + ph_b1) -> reuse imgbf buffer
  gemm_bf16<<<ggrid, 256, 0, stream>>>(fusbf, Wt2, ph_b1, add2, nullptr, imgbf, 1, accT2s, accT2q);

  finalize_kernel<<<1, 512, 0, stream>>>(accT1s, accT1q, ph_bn2_g, ph_bn2_b, a3s, a3h, invM, 1, 0);
  finalize_kernel<<<1, 512, 0, stream>>>(accT2s, accT2q, ph_bn2_g, ph_bn2_b, a4s, a4h, invM, 1, 0);

  wconv_kernel<<<wgrid, 256, 0, stream>>>(ph_w2, a3s, a3h, Wt3, add3);
  wconv_kernel<<<wgrid, 256, 0, stream>>>(ph_w2, a4s, a4h, Wt4, add4);

  // final projections straight into d_out halves (fp32, no activation)
  gemm_bf16<<<ggrid, 256, 0, stream>>>(xbf, Wt3, ph_b2, add3, out, nullptr, 0, nullptr, nullptr);
  gemm_bf16<<<ggrid, 256, 0, stream>>>(imgbf, Wt4, ph_b2, add4, out + BD, nullptr, 0, nullptr, nullptr);

  // row-wise L2 normalize both outputs in place
  l2norm_kernel<<<(2 * NROWS) / 4, 256, 0, stream>>>(out);
}

// Round 5
// 509.126 us; speedup vs baseline: 1.4840x; 1.0238x over previous
//
#include <hip/hip_runtime.h>
#include <cmath>

// Problem constants
#define NROWS 16384
#define DDIM  512

typedef __attribute__((ext_vector_type(8))) short          bf16x8;
typedef __attribute__((ext_vector_type(4))) float          f32x4;
typedef __attribute__((ext_vector_type(8))) unsigned short u16x8;
typedef __attribute__((ext_vector_type(4))) unsigned short u16x4;

__device__ __forceinline__ unsigned short f2bf(float f) {
  unsigned u = __float_as_uint(f);
  u += 0x7fffu + ((u >> 16) & 1u);  // RNE; inputs finite
  return (unsigned short)(u >> 16);
}

__device__ __forceinline__ float gelu_tanh(float x) {
  float x3 = x * x * x;
  float t = tanhf(0.79788456080286535588f * (x + 0.044715f * x3));
  return 0.5f * x * (1.0f + t);
}

__device__ __forceinline__ void ld8(const float* p, float* v) {
  float4 a = *(const float4*)p;
  float4 b = *(const float4*)(p + 256);
  v[0] = a.x; v[1] = a.y; v[2] = a.z; v[3] = a.w;
  v[4] = b.x; v[5] = b.y; v[6] = b.z; v[7] = b.w;
}

__device__ __forceinline__ void st8(float* p, const float* v) {
  *(float4*)p = make_float4(v[0], v[1], v[2], v[3]);
  *(float4*)(p + 256) = make_float4(v[4], v[5], v[6], v[7]);
}

__device__ __forceinline__ float wave_sum(float v) {
#pragma unroll
  for (int m = 1; m < 64; m <<= 1) v += __shfl_xor(v, m, 64);
  return v;
}

// async global -> LDS, 16B per lane (LDS dest = wave-uniform base + lane*16)
__device__ __forceinline__ void gload_lds16(const void* g, void* l) {
  __builtin_amdgcn_global_load_lds(
      (const __attribute__((address_space(1))) unsigned int*)g,
      (__attribute__((address_space(3))) unsigned int*)l, 16, 0, 0);
}

// ---------------------------------------------------------------------------
// Kernel 1: per-row prep (FROZEN from round 4 — 119us, VALUBusy 22%).
// Gate numerics bit-identical to round 3.
// ---------------------------------------------------------------------------
__global__ __launch_bounds__(256) void prep_kernel(
    const float* __restrict__ img, const float* __restrict__ txt,
    const float* __restrict__ wg_w1, const float* __restrict__ wg_b1,
    const float* __restrict__ wg_w2, const float* __restrict__ wg_b2,
    const float* __restrict__ conv_w, const float* __restrict__ conv_b,
    unsigned short* __restrict__ xbf, unsigned short* __restrict__ imgbf,
    float* __restrict__ accPart) {
  __shared__ float csX[512], cqX[512], csI[512], cqI[512];
  const int tid = threadIdx.x;
  for (int i = tid; i < 512; i += 256) {
    csX[i] = 0.f; cqX[i] = 0.f; csI[i] = 0.f; cqI[i] = 0.f;
  }
  __syncthreads();

  const int lane = tid & 63;
  const int gwave = blockIdx.x * 4 + (tid >> 6);  // 0..2047

  const float cb = conv_b[0];
  const float b2f = wg_b2[0];
  float w1f[16], b1f[16], w2f[16];
#pragma unroll
  for (int i = 0; i < 16; i++) {
    w1f[i] = wg_w1[i]; b1f[i] = wg_b1[i]; w2f[i] = wg_w2[i];
  }
  float cw[5];
#pragma unroll
  for (int k = 0; k < 5; k++) cw[k] = conv_w[k];

  float sX[8] = {0, 0, 0, 0, 0, 0, 0, 0}, qX[8] = {0, 0, 0, 0, 0, 0, 0, 0};
  float sI[8] = {0, 0, 0, 0, 0, 0, 0, 0}, qI[8] = {0, 0, 0, 0, 0, 0, 0, 0};

  for (int it = 0; it < 8; it++) {
    const int r = gwave * 8 + it;
    const float* ip = img + (size_t)r * DDIM + lane * 4;
    float iv[8];
    ld8(ip, iv);

    {
      u16x4 lo, hi;
#pragma unroll
      for (int j = 0; j < 4; j++) { lo[j] = f2bf(iv[j]); hi[j] = f2bf(iv[4 + j]); }
      *(u16x4*)(imgbf + (size_t)r * DDIM + lane * 4) = lo;
      *(u16x4*)(imgbf + (size_t)r * DDIM + 256 + lane * 4) = hi;
    }
#pragma unroll
    for (int j = 0; j < 8; j++) { sI[j] += iv[j]; qI[j] += iv[j] * iv[j]; }

    float tv[5][8];
#pragma unroll
    for (int k = 0; k < 5; k++)
      ld8(txt + ((size_t)r * 5 + k) * DDIM + lane * 4, tv[k]);

    double ss = 0.0;
    double s2[5], dp[5];
#pragma unroll
    for (int k = 0; k < 5; k++) { s2[k] = 0.0; dp[k] = 0.0; }
#pragma unroll
    for (int j = 0; j < 8; j++) {
      ss += (double)iv[j] * (double)iv[j];
#pragma unroll
      for (int k = 0; k < 5; k++) {
        s2[k] += (double)tv[k][j] * (double)tv[k][j];
        dp[k] += (double)iv[j] * (double)tv[k][j];
      }
    }

#pragma unroll
    for (int m = 1; m < 64; m <<= 1) {
      ss += __shfl_xor(ss, m, 64);
#pragma unroll
      for (int k = 0; k < 5; k++) {
        s2[k] += __shfl_xor(s2[k], m, 64);
        dp[k] += __shfl_xor(dp[k], m, 64);
      }
    }
    const double dimg = fmax(sqrt(ss), 1e-12);

    double simv[5];
#pragma unroll
    for (int k = 0; k < 5; k++) {
      const double dt = fmax(sqrt(s2[k]), 1e-12);
      simv[k] = dp[k] / (dimg * dt);
    }

    double o[5];
#pragma unroll
    for (int k = 0; k < 5; k++) o[k] = (double)b2f;
#pragma unroll
    for (int i = 0; i < 16; i++) {
      const double w1d = (double)w1f[i];
      const double b1d = (double)b1f[i];
      const double w2d = (double)w2f[i];
#pragma unroll
      for (int k = 0; k < 5; k++) {
        double h = simv[k] * w1d + b1d;
        h = fmax(h, 0.0);
        o[k] += h * w2d;
      }
    }
    float wv[5];
#pragma unroll
    for (int k = 0; k < 5; k++) {
      float o32 = (float)o[k];
      float e32 = (float)exp(-(double)o32);  // correctly-rounded f32 exp
      float a32 = 1.0f + e32;
      wv[k] = 1.0f / a32;
    }

    float c[5];
#pragma unroll
    for (int k = 0; k < 5; k++) {
      int rk = 0;
#pragma unroll
      for (int j = 0; j < 5; j++)
        rk += (int)((wv[j] > wv[k]) || ((wv[j] == wv[k]) && (j < k)));
      c[k] = cw[rk] * wv[k];
    }

    float xv[8];
#pragma unroll
    for (int j = 0; j < 8; j++) {
      float v = cb;
#pragma unroll
      for (int k = 0; k < 5; k++) v = fmaf(c[k], tv[k][j], v);
      xv[j] = v;
    }
    {
      u16x4 lo, hi;
#pragma unroll
      for (int j = 0; j < 4; j++) { lo[j] = f2bf(xv[j]); hi[j] = f2bf(xv[4 + j]); }
      *(u16x4*)(xbf + (size_t)r * DDIM + lane * 4) = lo;
      *(u16x4*)(xbf + (size_t)r * DDIM + 256 + lane * 4) = hi;
    }

#pragma unroll
    for (int j = 0; j < 8; j++) { sX[j] += xv[j]; qX[j] += xv[j] * xv[j]; }
  }

  const int c0 = lane * 4, c1 = 256 + lane * 4;
#pragma unroll
  for (int j = 0; j < 4; j++) {
    atomicAdd(&csX[c0 + j], sX[j]);     atomicAdd(&cqX[c0 + j], qX[j]);
    atomicAdd(&csX[c1 + j], sX[4 + j]); atomicAdd(&cqX[c1 + j], qX[4 + j]);
    atomicAdd(&csI[c0 + j], sI[j]);     atomicAdd(&cqI[c0 + j], qI[j]);
    atomicAdd(&csI[c1 + j], sI[4 + j]); atomicAdd(&cqI[c1 + j], qI[4 + j]);
  }
  __syncthreads();
  float* base = accPart + (size_t)(blockIdx.x & 31) * 2048;
  for (int i = tid; i < 512; i += 256) {
    atomicAdd(&base[i], csX[i]);
    atomicAdd(&base[512 + i], cqX[i]);
    atomicAdd(&base[1024 + i], csI[i]);
    atomicAdd(&base[1536 + i], cqI[i]);
  }
}

// ---------------------------------------------------------------------------
// Weight prep WITH folded BN-finalize (round-5: removes 6 single-block
// launches). Each block recomputes its 32 scale/shift values from raw
// (multi-copy) stats — same copy-sum order as the old finalize_kernel,
// bit-identical affine params.
//   Wt[n][k] = bf16(scale[k] * W[k][n]);  addv[n] += sum_k shift[k]*W[k][n]
// ---------------------------------------------------------------------------
__global__ __launch_bounds__(256) void wconv_kernel(
    const float* __restrict__ W,
    const float* __restrict__ s, const float* __restrict__ q,
    const float* __restrict__ g, const float* __restrict__ b,
    float invM, int ncopies, int stride,
    unsigned short* __restrict__ Wt, float* __restrict__ addv) {
  __shared__ float T[32][33];
  __shared__ float P[32];
  __shared__ float SC[32], SH[32];
  const int t = threadIdx.x;
  const int k0 = blockIdx.x * 32, n0 = blockIdx.y * 32;
  {
    int r = t >> 3, c = (t & 7) * 4;
    float4 v = *(const float4*)&W[(size_t)(k0 + r) * 512 + n0 + c];
    T[r][c] = v.x; T[r][c + 1] = v.y; T[r][c + 2] = v.z; T[r][c + 3] = v.w;
  }
  if (t < 32) {
    P[t] = 0.f;
    const int j = k0 + t;
    float ss = 0.f, qq = 0.f;
    for (int c = 0; c < ncopies; c++) {
      ss += s[(size_t)c * stride + j];
      qq += q[(size_t)c * stride + j];
    }
    float m = ss * invM;
    float v = qq * invM - m * m;
    float r = 1.0f / sqrtf(v + 1e-5f);
    float sc = g[j] * r;
    SC[t] = sc;
    SH[t] = fmaf(-m, sc, b[j]);
  }
  __syncthreads();
  {
    int n = t >> 3, k = (t & 7) * 4;
    u16x4 o;
#pragma unroll
    for (int i = 0; i < 4; i++) o[i] = f2bf(T[k + i][n] * SC[k + i]);
    *(u16x4*)&Wt[(size_t)(n0 + n) * 512 + k0 + k] = o;
  }
  {
    int n = t & 31, rb = (t >> 5) * 4;
    float p = 0.f;
#pragma unroll
    for (int i = 0; i < 4; i++) p += SH[rb + i] * T[rb + i][n];
    atomicAdd(&P[n], p);
  }
  __syncthreads();
  if (t < 32) atomicAdd(&addv[n0 + t], P[t]);
}

// ---------------------------------------------------------------------------
// bf16 MFMA GEMM: C = act( A @ Wt^T + bias + addv ). Tile 128x128, BK=32,
// 4 waves (2x2), 16x16x32 MFMA, 4x4 acc/wave. Round-5: staging switched from
// reg-staged LDS writes to global_load_lds width=16 (m97 pattern: LDS dest
// linear = wave base + lane*16; XOR swizzle applied on the GLOBAL source
// address, unchanged from before -> bit-identical LDS contents).
// Dual-problem support: blocks with bx >= mblocks process the second set
// (fuses the two independent final projections into one launch).
// ---------------------------------------------------------------------------
__global__ __launch_bounds__(256) void gemm_bf16(
    const unsigned short* __restrict__ A, const unsigned short* __restrict__ Wt,
    const float* __restrict__ bias, const float* __restrict__ addv,
    float* __restrict__ Cf, unsigned short* __restrict__ Cb, int do_gelu,
    float* __restrict__ accS, float* __restrict__ accQ,
    const unsigned short* __restrict__ A2, const unsigned short* __restrict__ W2,
    const float* __restrict__ bias2, const float* __restrict__ addv2,
    float* __restrict__ Cf2, int mblocks) {
  __shared__ __align__(16) short As[128 * 32];
  __shared__ __align__(16) short Bs[128 * 32];
  __shared__ float colS[128], colQ[128];
  const int tid = threadIdx.x;
  const int ln = tid & 63;
  const int lq = ln >> 4, lr = ln & 15;
  const int wv = tid >> 6;
  const int wm = wv >> 1, wn = wv & 1;

  int bx = blockIdx.x;
  if (A2 && bx >= mblocks) {
    bx -= mblocks;
    A = A2; Wt = W2; bias = bias2; addv = addv2; Cf = Cf2; Cb = nullptr;
  }
  const int bm = bx * 128, bn = blockIdx.y * 128;

  f32x4 acc[4][4];
#pragma unroll
  for (int i = 0; i < 4; i++)
#pragma unroll
    for (int j = 0; j < 4; j++) acc[i][j] = (f32x4){0.f, 0.f, 0.f, 0.f};

  // staging: thread covers LDS 16B slots idx0=tid, idx1=256+tid. Slot idx
  // holds global (row r(idx), chunk (idx&3)^((r>>1)&3)) -> swizzle on the
  // global source, LDS written linearly (global_load_lds requirement).
  const int idx0 = tid, idx1 = 256 + tid;
  const int r0 = idx0 >> 2, k0g = (idx0 & 3) ^ ((r0 >> 1) & 3);
  const int r1 = idx1 >> 2, k1g = (idx1 & 3) ^ ((r1 >> 1) & 3);
  const unsigned short* ga0 = A + (size_t)(bm + r0) * 512 + k0g * 8;
  const unsigned short* ga1 = A + (size_t)(bm + r1) * 512 + k1g * 8;
  const unsigned short* gb0 = Wt + (size_t)(bn + r0) * 512 + k0g * 8;
  const unsigned short* gb1 = Wt + (size_t)(bn + r1) * 512 + k1g * 8;

  // wave-uniform LDS bases (chunk of 64 consecutive 16B slots per wave)
  const int wb = (tid >> 6) << 10;  // wave * 1024 bytes
  char* lA0 = (char*)As + wb;
  char* lA1 = (char*)As + 4096 + wb;
  char* lB0 = (char*)Bs + wb;
  char* lB1 = (char*)Bs + 4096 + wb;

  gload_lds16(ga0, lA0); gload_lds16(ga1, lA1);
  gload_lds16(gb0, lB0); gload_lds16(gb1, lB1);

  for (int kk = 0; kk < 512; kk += 32) {
    __syncthreads();  // drains vmcnt(0): tile kk resident in LDS
    bf16x8 af[4], bfr[4];
#pragma unroll
    for (int i = 0; i < 4; i++) {
      int r = wm * 64 + i * 16 + lr;
      af[i] = *(const bf16x8*)((const char*)As + r * 64 + ((lq ^ ((r >> 1) & 3)) << 4));
    }
#pragma unroll
    for (int j = 0; j < 4; j++) {
      int n = wn * 64 + j * 16 + lr;
      bfr[j] = *(const bf16x8*)((const char*)Bs + n * 64 + ((lq ^ ((n >> 1) & 3)) << 4));
    }
#pragma unroll
    for (int i = 0; i < 4; i++)
#pragma unroll
      for (int j = 0; j < 4; j++)
        acc[i][j] = __builtin_amdgcn_mfma_f32_16x16x32_bf16(af[i], bfr[j], acc[i][j], 0, 0, 0);
    __syncthreads();  // all waves done reading LDS
    if (kk + 32 < 512) {
      gload_lds16(ga0 + kk + 32, lA0); gload_lds16(ga1 + kk + 32, lA1);
      gload_lds16(gb0 + kk + 32, lB0); gload_lds16(gb1 + kk + 32, lB1);
    }
  }

  // epilogue
  const bool do_stats = (accS != nullptr);
  if (do_stats) {
    if (tid < 128) { colS[tid] = 0.f; colQ[tid] = 0.f; }
    __syncthreads();
  }
  float badd[4];
  int cols[4];
#pragma unroll
  for (int j = 0; j < 4; j++) {
    int c = bn + wn * 64 + j * 16 + lr;
    cols[j] = c;
    badd[j] = bias[c] + addv[c];
  }
#pragma unroll
  for (int j = 0; j < 4; j++) {
    float s = 0.f, q = 0.f;
#pragma unroll
    for (int i = 0; i < 4; i++) {
      int rbase = bm + wm * 64 + i * 16 + lq * 4;
#pragma unroll
      for (int rg = 0; rg < 4; rg++) {
        float v = acc[i][j][rg] + badd[j];
        if (do_gelu) v = gelu_tanh(v);
        size_t off = (size_t)(rbase + rg) * 512 + cols[j];
        if (Cb) Cb[off] = f2bf(v);
        else Cf[off] = v;
        s += v; q += v * v;
      }
    }
    if (do_stats) {
      atomicAdd(&colS[wn * 64 + j * 16 + lr], s);
      atomicAdd(&colQ[wn * 64 + j * 16 + lr], q);
    }
  }
  if (do_stats) {
    __syncthreads();
    if (tid < 128) {
      atomicAdd(&accS[bn + tid], colS[tid]);
      atomicAdd(&accQ[bn + tid], colQ[tid]);
    }
  }
}

// ---------------------------------------------------------------------------
// Final row L2 normalization, in place over d_out (32768 rows x 512)
// ---------------------------------------------------------------------------
__global__ __launch_bounds__(256) void l2norm_kernel(float* __restrict__ out) {
  const int wave = blockIdx.x * 4 + (threadIdx.x >> 6);
  const int lane = threadIdx.x & 63;
  float* p = out + (size_t)wave * DDIM + lane * 4;
  float v[8];
  ld8(p, v);
  float ss = 0.f;
#pragma unroll
  for (int j = 0; j < 8; j++) ss += v[j] * v[j];
  ss = wave_sum(ss);
  const float inv = 1.0f / sqrtf(ss);
#pragma unroll
  for (int j = 0; j < 8; j++) v[j] *= inv;
  st8(p, v);
}

extern "C" void kernel_launch(void* const* d_in, const int* in_sizes, int n_in,
                              void* d_out, int out_size, void* d_ws, size_t ws_size,
                              hipStream_t stream) {
  const float* img     = (const float*)d_in[0];
  const float* txt     = (const float*)d_in[1];
  const float* wg_w1   = (const float*)d_in[2];
  const float* wg_b1   = (const float*)d_in[3];
  const float* wg_w2   = (const float*)d_in[4];
  const float* wg_b2   = (const float*)d_in[5];
  const float* conv_w  = (const float*)d_in[6];
  const float* conv_b  = (const float*)d_in[7];
  const float* mg_bn_g = (const float*)d_in[8];
  const float* mg_bn_b = (const float*)d_in[9];
  const float* mg_w    = (const float*)d_in[10];
  const float* mg_b    = (const float*)d_in[11];
  const float* ph_bn1_g= (const float*)d_in[12];
  const float* ph_bn1_b= (const float*)d_in[13];
  const float* ph_w1   = (const float*)d_in[14];
  const float* ph_b1   = (const float*)d_in[15];
  const float* ph_bn2_g= (const float*)d_in[16];
  const float* ph_bn2_b= (const float*)d_in[17];
  const float* ph_w2   = (const float*)d_in[18];
  const float* ph_b2   = (const float*)d_in[19];
  float* out = (float*)d_out;

  const size_t BD = (size_t)NROWS * DDIM;
  const size_t WSZ = 512 * 512;

  unsigned short* xbf   = (unsigned short*)d_ws;  // later reused as t1img bf16
  unsigned short* imgbf = xbf + BD;               // later reused as t1f bf16
  unsigned short* fusbf = imgbf + BD;
  unsigned short* Wt0   = fusbf + BD;
  unsigned short* Wt1   = Wt0 + WSZ;
  unsigned short* Wt2   = Wt1 + WSZ;
  unsigned short* Wt3   = Wt2 + WSZ;
  unsigned short* Wt4   = Wt3 + WSZ;
  float* acc  = (float*)(Wt4 + WSZ);   // 10*512 gemm stats
  float* addv = acc + 10 * 512;        // 5*512 shift-row terms
  float* accPart = addv + 5 * 512;     // 32 copies x 4 arrays x 512

  float* accFs = acc + 4 * 512, *accFq = acc + 5 * 512;
  float* accT1s= acc + 6 * 512, *accT1q= acc + 7 * 512;
  float* accT2s= acc + 8 * 512, *accT2q= acc + 9 * 512;
  float* add0 = addv + 0 * 512, *add1 = addv + 1 * 512, *add2 = addv + 2 * 512;
  float* add3 = addv + 3 * 512, *add4 = addv + 4 * 512;

  // zero gemm-stats + addv + accPart in one memset (contiguous)
  hipMemsetAsync(acc, 0, (15 * 512 + 32 * 2048) * sizeof(float), stream);

  // prep emits xbf, imgbf, and 32-copy partial stats
  prep_kernel<<<512, 256, 0, stream>>>(img, txt, wg_w1, wg_b1, wg_w2, wg_b2,
                                       conv_w, conv_b, xbf, imgbf, accPart);
  const float invM = 1.0f / (float)NROWS;

  dim3 wgrid(16, 16);
  dim3 ggrid(NROWS / 128, DDIM / 128);
  dim3 dgrid(2 * NROWS / 128, DDIM / 128);

  // wconv computes BN affine in-block (finalize folded in)
  // X stats: accPart[c*2048 + {0,512}], I stats: {1024,1536}, 32 copies
  wconv_kernel<<<wgrid, 256, 0, stream>>>(mg_w, accPart + 0, accPart + 512,
                                          mg_bn_g, mg_bn_b, invM, 32, 2048, Wt0, add0);
  wconv_kernel<<<wgrid, 256, 0, stream>>>(ph_w1, accPart + 1024, accPart + 1536,
                                          ph_bn1_g, ph_bn1_b, invM, 32, 2048, Wt1, add1);

  // fused = gelu(BN0(x) @ mg_w + mg_b), stats(fused)
  gemm_bf16<<<ggrid, 256, 0, stream>>>(xbf, Wt0, mg_b, add0, nullptr, fusbf, 1,
                                       accFs, accFq,
                                       nullptr, nullptr, nullptr, nullptr, nullptr, 128);
  // t1_img = gelu(BN1(img) @ ph_w1 + ph_b1) -> reuse xbf buffer
  gemm_bf16<<<ggrid, 256, 0, stream>>>(imgbf, Wt1, ph_b1, add1, nullptr, xbf, 1,
                                       accT1s, accT1q,
                                       nullptr, nullptr, nullptr, nullptr, nullptr, 128);

  wconv_kernel<<<wgrid, 256, 0, stream>>>(ph_w1, accFs, accFq,
                                          ph_bn1_g, ph_bn1_b, invM, 1, 0, Wt2, add2);
  // t1_fused = gelu(BN2(fused) @ ph_w1 + ph_b1) -> reuse imgbf buffer
  gemm_bf16<<<ggrid, 256, 0, stream>>>(fusbf, Wt2, ph_b1, add2, nullptr, imgbf, 1,
                                       accT2s, accT2q,
                                       nullptr, nullptr, nullptr, nullptr, nullptr, 128);

  wconv_kernel<<<wgrid, 256, 0, stream>>>(ph_w2, accT1s, accT1q,
                                          ph_bn2_g, ph_bn2_b, invM, 1, 0, Wt3, add3);
  wconv_kernel<<<wgrid, 256, 0, stream>>>(ph_w2, accT2s, accT2q,
                                          ph_bn2_g, ph_bn2_b, invM, 1, 0, Wt4, add4);

  // both final projections fused in ONE launch (independent problems):
  // lower half: t1img(xbf) @ Wt3 -> out; upper half: t1f(imgbf) @ Wt4 -> out+BD
  gemm_bf16<<<dgrid, 256, 0, stream>>>(xbf, Wt3, ph_b2, add3, out, nullptr, 0,
                                       nullptr, nullptr,
                                       imgbf, Wt4, ph_b2, add4, out + BD, 128);

  // row-wise L2 normalize both outputs in place
  l2norm_kernel<<<(2 * NROWS) / 4, 256, 0, stream>>>(out);
}